// Round 5
// baseline (2957.891 us; speedup 1.0000x reference)
//
#include <hip/hip_runtime.h>
#include <hip/hip_bf16.h>
#include <cstdint>
#include <cstddef>

#define CH    64
#define IMG   512
#define PLANE (IMG * IMG)   // 262144
#define NSPX  256

// ===========================================================================
// FAST PATH: blockify (pure permutation) + round-3-bit-exact pool/iter/gather
// ===========================================================================

// ---------------------------------------------------------------------------
// Blockify: fb[(b*256+sp)][c][p] = f[b, c, (sp>>4)*32 + p/32, (sp&15)*32 + p%32]
// One wg per (b, sr, c): reads the contiguous 64 KB slab
// f[b, c, sr*32:(sr+1)*32, :] with perfectly dense float4 loads and writes
// 16 block-channel planes (4 KB each, dense). NO arithmetic — pure copy.
// ---------------------------------------------------------------------------
__global__ __launch_bounds__(256) void ssn_blockify(
    const float* __restrict__ f, float* __restrict__ fb) {
  const int wg = blockIdx.x;                 // ((b*16)+sr)*64 + c
  const int c = wg & 63, sr = (wg >> 6) & 15, b = wg >> 10;
  const int tid = threadIdx.x;
  const float* slab = f + (size_t)(b * CH + c) * PLANE + (size_t)(sr * 32) * IMG;
  #pragma unroll
  for (int it = 0; it < 16; ++it) {
    const int flat = it * 1024 + tid * 4;    // float index in the 16384-float slab
    float4 v = *(const float4*)(slab + flat);
    const int y = flat >> 9, x = flat & 511;
    const int sc = x >> 5, p = (y << 5) | (x & 31);
    float* dst = fb + ((size_t)((b << 8) + sr * 16 + sc) * CH + c) * 1024 + p;
    *(float4*)dst = v;
  }
}

// ---------------------------------------------------------------------------
// Pool from fb: lane = channel, strictly sequential row-major chain over the
// 1024 block pixels — identical op order to round 3's ssn_pool (bit-exact).
// ---------------------------------------------------------------------------
__global__ __launch_bounds__(64) void ssn_pool_blk(const float* __restrict__ fb,
                                                   float* __restrict__ numer,
                                                   float* __restrict__ denom) {
  const int wg = blockIdx.x;            // b*256 + sp
  const int c = threadIdx.x;            // 0..63
  const float4* q = (const float4*)(fb + ((size_t)wg * CH + c) * 1024);
  float acc = 0.f;
  #pragma unroll 8
  for (int xv = 0; xv < 256; ++xv) {
    float4 v = q[xv];
    acc = __fadd_rn(acc, v.x);
    acc = __fadd_rn(acc, v.y);
    acc = __fadd_rn(acc, v.z);
    acc = __fadd_rn(acc, v.w);
  }
  numer[((size_t)wg << 6) + c] = acc;
  if (c == 0) denom[wg] = 1024.0f;
}

// ---------------------------------------------------------------------------
// One SSN iteration — round 3's ssn_iter VERBATIM except the f loads are
// redirected into the blocked layout (identical values, dense addresses).
// ---------------------------------------------------------------------------
__global__ __launch_bounds__(256, 3) void ssn_iter_blk(const float* __restrict__ fb,
    const float* __restrict__ numer_in, const float* __restrict__ denom_in,
    float* __restrict__ Pnum, float* __restrict__ Pden,
    float* __restrict__ labels_out, const int final_flag) {
  const int wg = blockIdx.x;
  const int b = wg >> 8, sp = wg & 255;
  const int sr = sp >> 4, sc = sp & 15;
  const int tid = threadIdx.x;
  const int wave = tid >> 6, lane = tid & 63;
  const int p = lane & 31, h = lane >> 5;   // pixel-in-row, channel-half

  __shared__ float cent[9][64];
  __shared__ float nw[4][9][64];
  __shared__ float dw[4][9];
  __shared__ int   nbr_s[9];
  __shared__ __align__(16) float v_lds[4][32][65];
  __shared__ __align__(16) float w_lds[4][32][12];

  if (tid < 9) {
    int dr = tid / 3 - 1, dc = tid % 3 - 1;
    int nr = sr + dr, nc = sc + dc;
    bool valid = (nr >= 0) && (nr < 16) && (nc >= 0) && (nc < 16);
    nbr_s[tid] = valid ? (nr * 16 + nc) : -1;
  }
  __syncthreads();
  for (int i = tid; i < 9 * 64; i += 256) {
    int k = i >> 6, c = i & 63;
    int ns = nbr_s[k];
    float v = 0.f;
    if (ns >= 0) {
      int base = (b << 8) + ns;
      v = numer_in[((size_t)base << 6) + c] / (denom_in[base] + 1e-16f);
    }
    cent[k][c] = v;
  }
  __syncthreads();

  int nbk[9];
  #pragma unroll
  for (int k = 0; k < 9; ++k) nbk[k] = nbr_s[k];

  float nacc[9], wsA[9];
  #pragma unroll
  for (int k = 0; k < 9; ++k) { nacc[k] = 0.f; wsA[k] = 0.f; }

  const int y0 = sr * 32, x0 = sc * 32;
  // blocked base for this wg's channel half: fb[wg][32h + cit][lrow*32 + p]
  const float* fpB = fb + ((size_t)wg * CH + 32 * h) * 1024;
  float (* __restrict__ vb)[65] = v_lds[wave];
  float (* __restrict__ wb)[12] = w_lds[wave];

  for (int r = 0; r < 8; ++r) {
    const int lrow = wave * 8 + r;
    const int gy = y0 + lrow;
    const float* fp = fpB + lrow * 32 + p;

    // ---- phase 1: lane ~ (pixel p, channel-half h) ----
    float dpart[9];
    #pragma unroll
    for (int k = 0; k < 9; ++k) dpart[k] = 0.f;
    #pragma unroll
    for (int cit = 0; cit < 32; ++cit) {
      float v = fp[(size_t)cit << 10];       // channel stride = 1024 floats
      vb[p][32 * h + cit] = v;
      #pragma unroll
      for (int k = 0; k < 9; ++k) {
        float d = v - cent[k][32 * h + cit];
        dpart[k] = fmaf(d, d, dpart[k]);
      }
    }
    float dist[9];
    #pragma unroll
    for (int k = 0; k < 9; ++k) {
      float o = __shfl_xor(dpart[k], 32);
      dist[k] = (nbk[k] >= 0) ? (dpart[k] + o) : __builtin_inff();
    }
    float m = dist[0];
    #pragma unroll
    for (int k = 1; k < 9; ++k) m = fminf(m, dist[k]);
    float w[9], s = 0.f;
    #pragma unroll
    for (int k = 0; k < 9; ++k) { w[k] = expf(m - dist[k]); s = __fadd_rn(s, w[k]); }
    #pragma unroll
    for (int k = 0; k < 9; ++k) w[k] = w[k] / s;

    if (final_flag) {
      float ba = w[0]; int bs = nbk[0];
      #pragma unroll
      for (int k = 1; k < 9; ++k)
        if (w[k] > ba) { ba = w[k]; bs = nbk[k]; }
      if (h == 0)
        labels_out[(size_t)b * PLANE + (size_t)gy * IMG + x0 + p] = (float)bs;
    }

    if (h == 0) {
      *(float4*)&wb[p][0] = make_float4(w[0], w[1], w[2], w[3]);
      *(float4*)&wb[p][4] = make_float4(w[4], w[5], w[6], w[7]);
      wb[p][8] = w[8];
    }

    // ---- phase 2: lane = channel c; mul-then-add (no fma) ----
    #pragma unroll 8
    for (int pp = 0; pp < 32; ++pp) {
      float v  = vb[pp][lane];
      float4 wA = *(const float4*)&wb[pp][0];
      float4 wB = *(const float4*)&wb[pp][4];
      float  w8 = wb[pp][8];
      nacc[0] = __fadd_rn(nacc[0], __fmul_rn(wA.x, v));
      nacc[1] = __fadd_rn(nacc[1], __fmul_rn(wA.y, v));
      nacc[2] = __fadd_rn(nacc[2], __fmul_rn(wA.z, v));
      nacc[3] = __fadd_rn(nacc[3], __fmul_rn(wA.w, v));
      nacc[4] = __fadd_rn(nacc[4], __fmul_rn(wB.x, v));
      nacc[5] = __fadd_rn(nacc[5], __fmul_rn(wB.y, v));
      nacc[6] = __fadd_rn(nacc[6], __fmul_rn(wB.z, v));
      nacc[7] = __fadd_rn(nacc[7], __fmul_rn(wB.w, v));
      nacc[8] = __fadd_rn(nacc[8], __fmul_rn(w8,  v));
      wsA[0] = __fadd_rn(wsA[0], wA.x);
      wsA[1] = __fadd_rn(wsA[1], wA.y);
      wsA[2] = __fadd_rn(wsA[2], wA.z);
      wsA[3] = __fadd_rn(wsA[3], wA.w);
      wsA[4] = __fadd_rn(wsA[4], wB.x);
      wsA[5] = __fadd_rn(wsA[5], wB.y);
      wsA[6] = __fadd_rn(wsA[6], wB.z);
      wsA[7] = __fadd_rn(wsA[7], wB.w);
      wsA[8] = __fadd_rn(wsA[8], w8);
    }
  }

  #pragma unroll
  for (int k = 0; k < 9; ++k) nw[wave][k][lane] = nacc[k];
  if (lane == 0) {
    #pragma unroll
    for (int k = 0; k < 9; ++k) dw[wave][k] = wsA[k];
  }
  __syncthreads();

  for (int i = tid; i < 9 * 64; i += 256) {
    int k = i >> 6, c = i & 63;
    float s01  = __fadd_rn(nw[0][k][c], nw[1][k][c]);
    float s012 = __fadd_rn(s01, nw[2][k][c]);
    Pnum[((size_t)wg * 9 + k) * 64 + c] = __fadd_rn(s012, nw[3][k][c]);
  }
  if (tid < 9) {
    float s01  = __fadd_rn(dw[0][tid], dw[1][tid]);
    float s012 = __fadd_rn(s01, dw[2][tid]);
    Pden[wg * 9 + tid] = __fadd_rn(s012, dw[3][tid]);
  }
}

// ---------------------------------------------------------------------------
// Deterministic gather: k ASCENDING (matches reference's numer += seg_sum_k).
// final_mode: write spix = numer/(denom+1e-16) instead. (Round 3 verbatim.)
// ---------------------------------------------------------------------------
__global__ __launch_bounds__(64) void ssn_gather(const float* __restrict__ Pnum,
    const float* __restrict__ Pden, float* __restrict__ numer_out,
    float* __restrict__ denom_out, float* __restrict__ spix_out,
    const int final_mode) {
  const int wg = blockIdx.x;           // b*256 + sp
  const int b = wg >> 8, sp = wg & 255;
  const int sr = sp >> 4, sc = sp & 15;
  const int c = threadIdx.x;           // 0..63
  float acc = 0.f, den = 0.f;
  #pragma unroll
  for (int k = 0; k < 9; ++k) {
    int dr = k / 3 - 1, dc = k % 3 - 1;
    int ssr = sr - dr, ssc = sc - dc;
    if (ssr >= 0 && ssr < 16 && ssc >= 0 && ssc < 16) {
      int src = (b << 8) + ssr * 16 + ssc;
      acc = __fadd_rn(acc, Pnum[((size_t)src * 9 + k) * 64 + c]);
      den = __fadd_rn(den, Pden[src * 9 + k]);
    }
  }
  if (final_mode) {
    spix_out[((size_t)wg << 6) + c] = acc / (den + 1e-16f);
  } else {
    numer_out[((size_t)wg << 6) + c] = acc;
    if (c == 0) denom_out[wg] = den;
  }
}

// ===========================================================================
// FALLBACK PATH (round-3 kernels, verbatim) — used if ws_size is too small
// ===========================================================================

__global__ __launch_bounds__(64) void ssn_pool(const float* __restrict__ f,
                                               float* __restrict__ numer,
                                               float* __restrict__ denom) {
  const int wg = blockIdx.x;
  const int b = wg >> 8, sp = wg & 255;
  const int sr = sp >> 4, sc = sp & 15;
  const int c = threadIdx.x;
  const int y0 = sr * 32, x0 = sc * 32;
  const float* base = f + (size_t)(b * CH + c) * PLANE;
  float acc = 0.f;
  for (int y = 0; y < 32; ++y) {
    const float4* rp = (const float4*)(base + (size_t)(y0 + y) * IMG + x0);
    #pragma unroll
    for (int xv = 0; xv < 8; ++xv) {
      float4 v = rp[xv];
      acc = __fadd_rn(acc, v.x);
      acc = __fadd_rn(acc, v.y);
      acc = __fadd_rn(acc, v.z);
      acc = __fadd_rn(acc, v.w);
    }
  }
  numer[((size_t)wg << 6) + c] = acc;
  if (c == 0) denom[wg] = 1024.0f;
}

__global__ __launch_bounds__(256, 3) void ssn_iter(const float* __restrict__ f,
    const float* __restrict__ numer_in, const float* __restrict__ denom_in,
    float* __restrict__ Pnum, float* __restrict__ Pden,
    float* __restrict__ labels_out, const int final_flag) {
  const int wg = blockIdx.x;
  const int b = wg >> 8, sp = wg & 255;
  const int sr = sp >> 4, sc = sp & 15;
  const int tid = threadIdx.x;
  const int wave = tid >> 6, lane = tid & 63;
  const int p = lane & 31, h = lane >> 5;

  __shared__ float cent[9][64];
  __shared__ float nw[4][9][64];
  __shared__ float dw[4][9];
  __shared__ int   nbr_s[9];
  __shared__ __align__(16) float v_lds[4][32][65];
  __shared__ __align__(16) float w_lds[4][32][12];

  if (tid < 9) {
    int dr = tid / 3 - 1, dc = tid % 3 - 1;
    int nr = sr + dr, nc = sc + dc;
    bool valid = (nr >= 0) && (nr < 16) && (nc >= 0) && (nc < 16);
    nbr_s[tid] = valid ? (nr * 16 + nc) : -1;
  }
  __syncthreads();
  for (int i = tid; i < 9 * 64; i += 256) {
    int k = i >> 6, c = i & 63;
    int ns = nbr_s[k];
    float v = 0.f;
    if (ns >= 0) {
      int base = (b << 8) + ns;
      v = numer_in[((size_t)base << 6) + c] / (denom_in[base] + 1e-16f);
    }
    cent[k][c] = v;
  }
  __syncthreads();

  int nbk[9];
  #pragma unroll
  for (int k = 0; k < 9; ++k) nbk[k] = nbr_s[k];

  float nacc[9], wsA[9];
  #pragma unroll
  for (int k = 0; k < 9; ++k) { nacc[k] = 0.f; wsA[k] = 0.f; }

  const int y0 = sr * 32, x0 = sc * 32;
  float (* __restrict__ vb)[65] = v_lds[wave];
  float (* __restrict__ wb)[12] = w_lds[wave];

  for (int r = 0; r < 8; ++r) {
    const int gy = y0 + wave * 8 + r;
    const float* fp = f + (size_t)(b * CH + 32 * h) * PLANE + (size_t)gy * IMG + x0 + p;

    float dpart[9];
    #pragma unroll
    for (int k = 0; k < 9; ++k) dpart[k] = 0.f;
    #pragma unroll
    for (int cit = 0; cit < 32; ++cit) {
      float v = fp[(size_t)cit * PLANE];
      vb[p][32 * h + cit] = v;
      #pragma unroll
      for (int k = 0; k < 9; ++k) {
        float d = v - cent[k][32 * h + cit];
        dpart[k] = fmaf(d, d, dpart[k]);
      }
    }
    float dist[9];
    #pragma unroll
    for (int k = 0; k < 9; ++k) {
      float o = __shfl_xor(dpart[k], 32);
      dist[k] = (nbk[k] >= 0) ? (dpart[k] + o) : __builtin_inff();
    }
    float m = dist[0];
    #pragma unroll
    for (int k = 1; k < 9; ++k) m = fminf(m, dist[k]);
    float w[9], s = 0.f;
    #pragma unroll
    for (int k = 0; k < 9; ++k) { w[k] = expf(m - dist[k]); s = __fadd_rn(s, w[k]); }
    #pragma unroll
    for (int k = 0; k < 9; ++k) w[k] = w[k] / s;

    if (final_flag) {
      float ba = w[0]; int bs = nbk[0];
      #pragma unroll
      for (int k = 1; k < 9; ++k)
        if (w[k] > ba) { ba = w[k]; bs = nbk[k]; }
      if (h == 0)
        labels_out[(size_t)b * PLANE + (size_t)gy * IMG + x0 + p] = (float)bs;
    }

    if (h == 0) {
      *(float4*)&wb[p][0] = make_float4(w[0], w[1], w[2], w[3]);
      *(float4*)&wb[p][4] = make_float4(w[4], w[5], w[6], w[7]);
      wb[p][8] = w[8];
    }

    #pragma unroll 8
    for (int pp = 0; pp < 32; ++pp) {
      float v  = vb[pp][lane];
      float4 wA = *(const float4*)&wb[pp][0];
      float4 wB = *(const float4*)&wb[pp][4];
      float  w8 = wb[pp][8];
      nacc[0] = __fadd_rn(nacc[0], __fmul_rn(wA.x, v));
      nacc[1] = __fadd_rn(nacc[1], __fmul_rn(wA.y, v));
      nacc[2] = __fadd_rn(nacc[2], __fmul_rn(wA.z, v));
      nacc[3] = __fadd_rn(nacc[3], __fmul_rn(wA.w, v));
      nacc[4] = __fadd_rn(nacc[4], __fmul_rn(wB.x, v));
      nacc[5] = __fadd_rn(nacc[5], __fmul_rn(wB.y, v));
      nacc[6] = __fadd_rn(nacc[6], __fmul_rn(wB.z, v));
      nacc[7] = __fadd_rn(nacc[7], __fmul_rn(wB.w, v));
      nacc[8] = __fadd_rn(nacc[8], __fmul_rn(w8,  v));
      wsA[0] = __fadd_rn(wsA[0], wA.x);
      wsA[1] = __fadd_rn(wsA[1], wA.y);
      wsA[2] = __fadd_rn(wsA[2], wA.z);
      wsA[3] = __fadd_rn(wsA[3], wA.w);
      wsA[4] = __fadd_rn(wsA[4], wB.x);
      wsA[5] = __fadd_rn(wsA[5], wB.y);
      wsA[6] = __fadd_rn(wsA[6], wB.z);
      wsA[7] = __fadd_rn(wsA[7], wB.w);
      wsA[8] = __fadd_rn(wsA[8], w8);
    }
  }

  #pragma unroll
  for (int k = 0; k < 9; ++k) nw[wave][k][lane] = nacc[k];
  if (lane == 0) {
    #pragma unroll
    for (int k = 0; k < 9; ++k) dw[wave][k] = wsA[k];
  }
  __syncthreads();

  for (int i = tid; i < 9 * 64; i += 256) {
    int k = i >> 6, c = i & 63;
    float s01  = __fadd_rn(nw[0][k][c], nw[1][k][c]);
    float s012 = __fadd_rn(s01, nw[2][k][c]);
    Pnum[((size_t)wg * 9 + k) * 64 + c] = __fadd_rn(s012, nw[3][k][c]);
  }
  if (tid < 9) {
    float s01  = __fadd_rn(dw[0][tid], dw[1][tid]);
    float s012 = __fadd_rn(s01, dw[2][tid]);
    Pden[wg * 9 + tid] = __fadd_rn(s012, dw[3][tid]);
  }
}

// ===========================================================================
extern "C" void kernel_launch(void* const* d_in, const int* in_sizes, int n_in,
                              void* d_out, int out_size, void* d_ws, size_t ws_size,
                              hipStream_t stream) {
  const float* f = (const float*)d_in[0];
  float* out = (float*)d_out;
  float* ws  = (float*)d_ws;
  float* labels = out + 4 * NSPX * CH;

  const size_t FB_FLOATS = (size_t)4 * NSPX * CH * 1024;     // 67,108,864
  const size_t SCRATCH_FLOATS = 589824 + 9216 + 2 * 65536 + 2 * 1024;
  const bool fast = ws_size >= (FB_FLOATS + SCRATCH_FLOATS) * sizeof(float);

  if (fast) {
    float* fb     = ws;
    float* Pnum   = ws + FB_FLOATS;
    float* Pden   = Pnum + 589824;
    float* numerA = Pden + 9216;
    float* numerB = numerA + 65536;
    float* denomA = numerB + 65536;
    float* denomB = denomA + 1024;

    ssn_blockify<<<dim3(4096), dim3(256), 0, stream>>>(f, fb);
    ssn_pool_blk<<<dim3(1024), dim3(64), 0, stream>>>(fb, numerA, denomA);

    float* ni = numerA; float* di = denomA;
    float* no = numerB; float* dn = denomB;
    for (int it = 0; it < 5; ++it) {
      ssn_iter_blk<<<dim3(1024), dim3(256), 0, stream>>>(fb, ni, di, Pnum, Pden,
                                                         labels, (it == 4) ? 1 : 0);
      if (it < 4) {
        ssn_gather<<<dim3(1024), dim3(64), 0, stream>>>(Pnum, Pden, no, dn, nullptr, 0);
        float* t;
        t = ni; ni = no; no = t;
        t = di; di = dn; dn = t;
      } else {
        ssn_gather<<<dim3(1024), dim3(64), 0, stream>>>(Pnum, Pden, nullptr, nullptr, out, 1);
      }
    }
  } else {
    float* Pnum   = ws;
    float* Pden   = ws + 589824;
    float* numerA = ws + 599040;
    float* numerB = ws + 664576;
    float* denomA = ws + 730112;
    float* denomB = ws + 731136;

    ssn_pool<<<dim3(1024), dim3(64), 0, stream>>>(f, numerA, denomA);

    float* ni = numerA; float* di = denomA;
    float* no = numerB; float* dn = denomB;
    for (int it = 0; it < 5; ++it) {
      ssn_iter<<<dim3(1024), dim3(256), 0, stream>>>(f, ni, di, Pnum, Pden, labels,
                                                     (it == 4) ? 1 : 0);
      if (it < 4) {
        ssn_gather<<<dim3(1024), dim3(64), 0, stream>>>(Pnum, Pden, no, dn, nullptr, 0);
        float* t;
        t = ni; ni = no; no = t;
        t = di; di = dn; dn = t;
      } else {
        ssn_gather<<<dim3(1024), dim3(64), 0, stream>>>(Pnum, Pden, nullptr, nullptr, out, 1);
      }
    }
  }
}

// Round 7
// 810.796 us; speedup vs baseline: 3.6481x; 3.6481x over previous
//
#include <hip/hip_runtime.h>
#include <hip/hip_bf16.h>
#include <cstdint>
#include <cstddef>

#define CH    64
#define IMG   512
#define PLANE (IMG * IMG)   // 262144
#define NSPX  256

// ---------------------------------------------------------------------------
// Pooling (round-3 verbatim, bit-exact): one 64-thread block per (b, sp);
// lane = channel; strictly sequential row-major __fadd_rn chain; denom=1024.
// ---------------------------------------------------------------------------
__global__ __launch_bounds__(64) void ssn_pool(const float* __restrict__ f,
                                               float* __restrict__ numer,
                                               float* __restrict__ denom) {
  const int wg = blockIdx.x;            // b*256 + sp
  const int b = wg >> 8, sp = wg & 255;
  const int sr = sp >> 4, sc = sp & 15;
  const int c = threadIdx.x;            // 0..63
  const int y0 = sr * 32, x0 = sc * 32;
  const float* base = f + (size_t)(b * CH + c) * PLANE;
  float acc = 0.f;
  for (int y = 0; y < 32; ++y) {
    const float4* rp = (const float4*)(base + (size_t)(y0 + y) * IMG + x0);
    #pragma unroll
    for (int xv = 0; xv < 8; ++xv) {
      float4 v = rp[xv];
      acc = __fadd_rn(acc, v.x);
      acc = __fadd_rn(acc, v.y);
      acc = __fadd_rn(acc, v.z);
      acc = __fadd_rn(acc, v.w);
    }
  }
  numer[((size_t)wg << 6) + c] = acc;
  if (c == 0) denom[wg] = 1024.0f;
}

// ---------------------------------------------------------------------------
// One SSN iteration. Identical arithmetic to rounds 3/5 (bit-exact); ONLY the
// global-load stage changed: per row, 8 float4 wave-loads (16 B/lane, 1 KB per
// instruction) stage the row's 64ch x 32px into the per-wave LDS transpose
// buffer; the distance chain then reads LDS in the original cit order.
// ---------------------------------------------------------------------------
__global__ __launch_bounds__(256, 3) void ssn_iter2(const float* __restrict__ f,
    const float* __restrict__ numer_in, const float* __restrict__ denom_in,
    float* __restrict__ Pnum, float* __restrict__ Pden,
    float* __restrict__ labels_out, const int final_flag) {
  const int wg = blockIdx.x;
  const int b = wg >> 8, sp = wg & 255;
  const int sr = sp >> 4, sc = sp & 15;
  const int tid = threadIdx.x;
  const int wave = tid >> 6, lane = tid & 63;
  const int p = lane & 31, h = lane >> 5;   // pixel-in-row, channel-half

  __shared__ float cent[9][64];
  __shared__ float nw[4][9][64];
  __shared__ float dw[4][9];
  __shared__ int   nbr_s[9];
  __shared__ __align__(16) float v_lds[4][32][65];  // [wave][px][ch], pad 65
  __shared__ __align__(16) float w_lds[4][32][12];  // 9 weights + pad

  if (tid < 9) {
    int dr = tid / 3 - 1, dc = tid % 3 - 1;
    int nr = sr + dr, nc = sc + dc;
    bool valid = (nr >= 0) && (nr < 16) && (nc >= 0) && (nc < 16);
    nbr_s[tid] = valid ? (nr * 16 + nc) : -1;
  }
  __syncthreads();
  // centroids = numer/(denom + 1e-16): same arithmetic as reference's spix
  for (int i = tid; i < 9 * 64; i += 256) {
    int k = i >> 6, c = i & 63;
    int ns = nbr_s[k];
    float v = 0.f;
    if (ns >= 0) {
      int base = (b << 8) + ns;
      v = numer_in[((size_t)base << 6) + c] / (denom_in[base] + 1e-16f);
    }
    cent[k][c] = v;
  }
  __syncthreads();

  int nbk[9];
  #pragma unroll
  for (int k = 0; k < 9; ++k) nbk[k] = nbr_s[k];

  float nacc[9], wsA[9];
  #pragma unroll
  for (int k = 0; k < 9; ++k) { nacc[k] = 0.f; wsA[k] = 0.f; }

  const int y0 = sr * 32, x0 = sc * 32;
  float (* __restrict__ vb)[65] = v_lds[wave];
  float (* __restrict__ wb)[12] = w_lds[wave];

  // staging decomposition: lane -> (channel-octet row, x-quad)
  const int cbase = lane >> 3;          // 0..7
  const int xq    = (lane & 7) * 4;     // 0,4,...,28

  for (int r = 0; r < 8; ++r) {
    const int gy = y0 + wave * 8 + r;

    // ---- staging: 8 x float4 wave-loads, 1 KB dense per instruction ----
    #pragma unroll
    for (int j = 0; j < 8; ++j) {
      const int c = j * 8 + cbase;
      const float4 v4 = *(const float4*)(
          f + (size_t)(b * CH + c) * PLANE + (size_t)gy * IMG + x0 + xq);
      vb[xq + 0][c] = v4.x;
      vb[xq + 1][c] = v4.y;
      vb[xq + 2][c] = v4.z;
      vb[xq + 3][c] = v4.w;
    }
    __builtin_amdgcn_wave_barrier();   // order staging before reads (no HW cost)

    // ---- phase 1: lane ~ (pixel p, channel-half h); bit-exact chain ----
    float dpart[9];
    #pragma unroll
    for (int k = 0; k < 9; ++k) dpart[k] = 0.f;
    #pragma unroll
    for (int cit = 0; cit < 32; ++cit) {
      float v = vb[p][32 * h + cit];
      #pragma unroll
      for (int k = 0; k < 9; ++k) {
        float d = v - cent[k][32 * h + cit];
        dpart[k] = fmaf(d, d, dpart[k]);
      }
    }
    float dist[9];
    #pragma unroll
    for (int k = 0; k < 9; ++k) {
      float o = __shfl_xor(dpart[k], 32);
      dist[k] = (nbk[k] >= 0) ? (dpart[k] + o) : __builtin_inff();
    }
    // softmax(-dist): exponent = m - dist, m = min(dist)
    float m = dist[0];
    #pragma unroll
    for (int k = 1; k < 9; ++k) m = fminf(m, dist[k]);
    float w[9], s = 0.f;
    #pragma unroll
    for (int k = 0; k < 9; ++k) { w[k] = expf(m - dist[k]); s = __fadd_rn(s, w[k]); }
    #pragma unroll
    for (int k = 0; k < 9; ++k) w[k] = w[k] / s;

    if (final_flag) {
      // argmax of normalized affinity, first occurrence on ties
      float ba = w[0]; int bs = nbk[0];
      #pragma unroll
      for (int k = 1; k < 9; ++k)
        if (w[k] > ba) { ba = w[k]; bs = nbk[k]; }
      if (h == 0)
        labels_out[(size_t)b * PLANE + (size_t)gy * IMG + x0 + p] = (float)bs;
    }

    if (h == 0) {
      *(float4*)&wb[p][0] = make_float4(w[0], w[1], w[2], w[3]);
      *(float4*)&wb[p][4] = make_float4(w[4], w[5], w[6], w[7]);
      wb[p][8] = w[8];
    }

    // ---- phase 2: lane = channel c; mul-then-add (no fma), same order ----
    #pragma unroll 8
    for (int pp = 0; pp < 32; ++pp) {
      float v  = vb[pp][lane];
      float4 wA = *(const float4*)&wb[pp][0];
      float4 wB = *(const float4*)&wb[pp][4];
      float  w8 = wb[pp][8];
      nacc[0] = __fadd_rn(nacc[0], __fmul_rn(wA.x, v));
      nacc[1] = __fadd_rn(nacc[1], __fmul_rn(wA.y, v));
      nacc[2] = __fadd_rn(nacc[2], __fmul_rn(wA.z, v));
      nacc[3] = __fadd_rn(nacc[3], __fmul_rn(wA.w, v));
      nacc[4] = __fadd_rn(nacc[4], __fmul_rn(wB.x, v));
      nacc[5] = __fadd_rn(nacc[5], __fmul_rn(wB.y, v));
      nacc[6] = __fadd_rn(nacc[6], __fmul_rn(wB.z, v));
      nacc[7] = __fadd_rn(nacc[7], __fmul_rn(wB.w, v));
      nacc[8] = __fadd_rn(nacc[8], __fmul_rn(w8,  v));
      wsA[0] = __fadd_rn(wsA[0], wA.x);
      wsA[1] = __fadd_rn(wsA[1], wA.y);
      wsA[2] = __fadd_rn(wsA[2], wA.z);
      wsA[3] = __fadd_rn(wsA[3], wA.w);
      wsA[4] = __fadd_rn(wsA[4], wB.x);
      wsA[5] = __fadd_rn(wsA[5], wB.y);
      wsA[6] = __fadd_rn(wsA[6], wB.z);
      wsA[7] = __fadd_rn(wsA[7], wB.w);
      wsA[8] = __fadd_rn(wsA[8], w8);
    }
    __builtin_amdgcn_wave_barrier();   // don't let next staging overlap reads
  }

  // per-wave partials -> LDS (no atomics)
  #pragma unroll
  for (int k = 0; k < 9; ++k) nw[wave][k][lane] = nacc[k];
  if (lane == 0) {
    #pragma unroll
    for (int k = 0; k < 9; ++k) dw[wave][k] = wsA[k];
  }
  __syncthreads();

  // fixed-order combine: wave0 + wave1 + wave2 + wave3
  for (int i = tid; i < 9 * 64; i += 256) {
    int k = i >> 6, c = i & 63;
    float s01  = __fadd_rn(nw[0][k][c], nw[1][k][c]);
    float s012 = __fadd_rn(s01, nw[2][k][c]);
    Pnum[((size_t)wg * 9 + k) * 64 + c] = __fadd_rn(s012, nw[3][k][c]);
  }
  if (tid < 9) {
    float s01  = __fadd_rn(dw[0][tid], dw[1][tid]);
    float s012 = __fadd_rn(s01, dw[2][tid]);
    Pden[wg * 9 + tid] = __fadd_rn(s012, dw[3][tid]);
  }
}

// ---------------------------------------------------------------------------
// Deterministic gather (round-3 verbatim): k ASCENDING matches the reference's
// numer += seg_sum_k order. final_mode: write spix = numer/(denom+1e-16).
// ---------------------------------------------------------------------------
__global__ __launch_bounds__(64) void ssn_gather(const float* __restrict__ Pnum,
    const float* __restrict__ Pden, float* __restrict__ numer_out,
    float* __restrict__ denom_out, float* __restrict__ spix_out,
    const int final_mode) {
  const int wg = blockIdx.x;           // b*256 + sp
  const int b = wg >> 8, sp = wg & 255;
  const int sr = sp >> 4, sc = sp & 15;
  const int c = threadIdx.x;           // 0..63
  float acc = 0.f, den = 0.f;
  #pragma unroll
  for (int k = 0; k < 9; ++k) {
    int dr = k / 3 - 1, dc = k % 3 - 1;
    int ssr = sr - dr, ssc = sc - dc;
    if (ssr >= 0 && ssr < 16 && ssc >= 0 && ssc < 16) {
      int src = (b << 8) + ssr * 16 + ssc;
      acc = __fadd_rn(acc, Pnum[((size_t)src * 9 + k) * 64 + c]);
      den = __fadd_rn(den, Pden[src * 9 + k]);
    }
  }
  if (final_mode) {
    spix_out[((size_t)wg << 6) + c] = acc / (den + 1e-16f);
  } else {
    numer_out[((size_t)wg << 6) + c] = acc;
    if (c == 0) denom_out[wg] = den;
  }
}

// ===========================================================================
extern "C" void kernel_launch(void* const* d_in, const int* in_sizes, int n_in,
                              void* d_out, int out_size, void* d_ws, size_t ws_size,
                              hipStream_t stream) {
  const float* f = (const float*)d_in[0];
  float* out = (float*)d_out;
  float* ws  = (float*)d_ws;
  float* labels = out + 4 * NSPX * CH;

  float* Pnum   = ws;                  // 1024*9*64 = 589824 f32
  float* Pden   = ws + 589824;         // 1024*9    =   9216 f32
  float* numerA = ws + 599040;         // 65536 f32
  float* numerB = ws + 664576;         // 65536 f32
  float* denomA = ws + 730112;         // 1024 f32
  float* denomB = ws + 731136;         // 1024 f32

  ssn_pool<<<dim3(1024), dim3(64), 0, stream>>>(f, numerA, denomA);

  float* ni = numerA; float* di = denomA;
  float* no = numerB; float* dn = denomB;
  for (int it = 0; it < 5; ++it) {
    ssn_iter2<<<dim3(1024), dim3(256), 0, stream>>>(f, ni, di, Pnum, Pden, labels,
                                                    (it == 4) ? 1 : 0);
    if (it < 4) {
      ssn_gather<<<dim3(1024), dim3(64), 0, stream>>>(Pnum, Pden, no, dn, nullptr, 0);
      float* t;
      t = ni; ni = no; no = t;
      t = di; di = dn; dn = t;
    } else {
      ssn_gather<<<dim3(1024), dim3(64), 0, stream>>>(Pnum, Pden, nullptr, nullptr, out, 1);
    }
  }
}